// Round 1
// baseline (453.623 us; speedup 1.0000x reference)
//
#include <hip/hip_runtime.h>

// Chamfer distance loss, brute force, fp32 VALU.
// N=65536 vertices (x), M=8192 samples (y), D=3.
// l1 = sum_m probs[m] * min_n d2(n,m)
// l2 = sum_n probs[argmin_m d2(n,m)] * min_m d2(n,m)
// out = l1 + l2  (single f32)

constexpr int NP = 65536;
constexpr int MP = 8192;
constexpr int CA = 8;   // m-chunks for K1 (rows): per-thread loop = MP/CA = 1024
constexpr int CB = 64;  // n-chunks for K2 (cols): per-thread loop = NP/CB = 1024

// ws layout (bytes):
//   [0,            NP*4)                    rowkey  (uint per n: d2bits&~0x1FFF | m)
//   [NP*4,         NP*4+MP*4)               colbits (uint per m: float bits of min d2)
//   [NP*4+MP*4,    +NP*16)                  xp (float4 packed x)
//   [...,          +MP*16)                  yp (float4 packed y)
// total ~1.44 MB

__global__ __launch_bounds__(256) void k0_init(const float* __restrict__ x,
                                               const float* __restrict__ y,
                                               unsigned* __restrict__ rowkey,
                                               unsigned* __restrict__ colbits,
                                               float4* __restrict__ xp,
                                               float4* __restrict__ yp,
                                               float* __restrict__ out) {
    int i = blockIdx.x * 256 + threadIdx.x;
    if (i < NP) {
        rowkey[i] = 0xFFFFFFFFu;
        xp[i] = make_float4(x[i * 3 + 0], x[i * 3 + 1], x[i * 3 + 2], 0.f);
    }
    if (i < MP) {
        colbits[i] = 0x7F800000u;  // +inf
        yp[i] = make_float4(y[i * 3 + 0], y[i * 3 + 1], y[i * 3 + 2], 0.f);
    }
    if (i == 0) out[0] = 0.f;
}

// rows: one thread per n, loop over an m-chunk; y read is wave-uniform -> s_load.
__global__ __launch_bounds__(256) void k1_rows(const float4* __restrict__ xp,
                                               const float4* __restrict__ yp,
                                               unsigned* __restrict__ rowkey) {
    int n = blockIdx.x * 256 + threadIdx.x;
    int m0 = blockIdx.y * (MP / CA);
    int m1 = m0 + (MP / CA);
    float4 xv = xp[n];
    float x0 = xv.x, x1 = xv.y, x2 = xv.z;
    unsigned kmin = 0xFFFFFFFFu;
#pragma unroll 4
    for (int m = m0; m < m1; ++m) {
        float4 yv = yp[m];  // uniform address
        float dx = x0 - yv.x;
        float dy = x1 - yv.y;
        float dz = x2 - yv.z;
        float d2 = fmaf(dx, dx, fmaf(dy, dy, dz * dz));  // >= 0 by construction
        unsigned key = (__float_as_uint(d2) & 0xFFFFE000u) | (unsigned)m;
        kmin = key < kmin ? key : kmin;
    }
    atomicMin(&rowkey[n], kmin);
}

// cols: one thread per m, loop over an n-chunk; x read is wave-uniform -> s_load.
__global__ __launch_bounds__(256) void k2_cols(const float4* __restrict__ xp,
                                               const float4* __restrict__ yp,
                                               unsigned* __restrict__ colbits) {
    int m = blockIdx.x * 256 + threadIdx.x;
    int n0 = blockIdx.y * (NP / CB);
    int n1 = n0 + (NP / CB);
    float4 yv = yp[m];
    float y0 = yv.x, y1 = yv.y, y2 = yv.z;
    float dmin = __builtin_inff();
#pragma unroll 4
    for (int n = n0; n < n1; ++n) {
        float4 xv = xp[n];  // uniform address
        float dx = xv.x - y0;
        float dy = xv.y - y1;
        float dz = xv.z - y2;
        float d2 = fmaf(dx, dx, fmaf(dy, dy, dz * dz));
        dmin = fminf(dmin, d2);
    }
    atomicMin(&colbits[m], __float_as_uint(dmin));  // d2 >= 0: uint order == float order
}

__global__ __launch_bounds__(256) void k3_reduce(const unsigned* __restrict__ rowkey,
                                                 const unsigned* __restrict__ colbits,
                                                 const float* __restrict__ probs,
                                                 float* __restrict__ out) {
    int i = blockIdx.x * 256 + threadIdx.x;
    float v = 0.f;
    if (i < NP) {
        unsigned k = rowkey[i];
        unsigned idx = k & 0x1FFFu;
        float dmin = __uint_as_float(k & 0xFFFFE000u);
        v = probs[idx] * dmin;  // l2 contribution
    } else {
        int m = i - NP;  // m < MP by grid construction
        float dmin = __uint_as_float(colbits[m]);
        v = probs[m] * dmin;  // l1 contribution
    }
    // block reduction: wave64 shuffle, then LDS across 4 waves
    for (int off = 32; off > 0; off >>= 1) v += __shfl_down(v, off, 64);
    __shared__ float wsum[4];
    int lane = threadIdx.x & 63;
    int w = threadIdx.x >> 6;
    if (lane == 0) wsum[w] = v;
    __syncthreads();
    if (threadIdx.x == 0) {
        atomicAdd(out, wsum[0] + wsum[1] + wsum[2] + wsum[3]);
    }
}

extern "C" void kernel_launch(void* const* d_in, const int* in_sizes, int n_in,
                              void* d_out, int out_size, void* d_ws, size_t ws_size,
                              hipStream_t stream) {
    const float* x = (const float*)d_in[0];      // [N,3]
    const float* y = (const float*)d_in[1];      // [M,3]
    const float* probs = (const float*)d_in[2];  // [M]
    float* out = (float*)d_out;

    char* ws = (char*)d_ws;
    unsigned* rowkey = (unsigned*)ws;
    unsigned* colbits = (unsigned*)(ws + (size_t)NP * 4);
    float4* xp = (float4*)(ws + (size_t)NP * 4 + (size_t)MP * 4);
    float4* yp = (float4*)(ws + (size_t)NP * 4 + (size_t)MP * 4 + (size_t)NP * 16);

    k0_init<<<NP / 256, 256, 0, stream>>>(x, y, rowkey, colbits, xp, yp, out);
    k1_rows<<<dim3(NP / 256, CA), 256, 0, stream>>>(xp, yp, rowkey);
    k2_cols<<<dim3(MP / 256, CB), 256, 0, stream>>>(xp, yp, colbits);
    k3_reduce<<<(NP + MP) / 256, 256, 0, stream>>>(rowkey, colbits, probs, out);
}

// Round 2
// 183.397 us; speedup vs baseline: 2.4734x; 2.4734x over previous
//
#include <hip/hip_runtime.h>

// Chamfer distance loss, brute force, fp32 VALU, register-tiled (T=8).
// N=65536 vertices (x), M=8192 samples (y), D=3.
// l1 = sum_m probs[m] * min_n d2(n,m)
// l2 = sum_n probs[argmin_m d2(n,m)] * min_m d2(n,m)
// out = l1 + l2  (single f32)

constexpr int NP = 65536;
constexpr int MP = 8192;
constexpr int T1 = 8;    // n-points per thread in k1
constexpr int CA = 32;   // m-chunks in k1: per-thread m-loop = MP/CA = 256
constexpr int T2 = 8;    // m-points per thread in k2
constexpr int CB = 256;  // n-chunks in k2: per-thread n-loop = NP/CB = 256

// ws layout (bytes):
//   [0,            NP*4)                    rowkey  (uint per n: d2bits&~0x1FFF | m)
//   [NP*4,         NP*4+MP*4)               colbits (uint per m: float bits of min d2)
//   [NP*4+MP*4,    +NP*16)                  xp (float4 packed x)
//   [...,          +MP*16)                  yp (float4 packed y)

__global__ __launch_bounds__(256) void k0_init(const float* __restrict__ x,
                                               const float* __restrict__ y,
                                               unsigned* __restrict__ rowkey,
                                               unsigned* __restrict__ colbits,
                                               float4* __restrict__ xp,
                                               float4* __restrict__ yp,
                                               float* __restrict__ out) {
    int i = blockIdx.x * 256 + threadIdx.x;
    if (i < NP) {
        rowkey[i] = 0xFFFFFFFFu;
        xp[i] = make_float4(x[i * 3 + 0], x[i * 3 + 1], x[i * 3 + 2], 0.f);
    }
    if (i < MP) {
        colbits[i] = 0x7F800000u;  // +inf
        yp[i] = make_float4(y[i * 3 + 0], y[i * 3 + 1], y[i * 3 + 2], 0.f);
    }
    if (i == 0) out[0] = 0.f;
}

// rows: each thread owns T1=8 n-points (block-strided), loops over an m-chunk.
// One yp load feeds 8 distance updates -> VALU-bound, 8 independent chains.
__global__ __launch_bounds__(256) void k1_rows(const float4* __restrict__ xp,
                                               const float4* __restrict__ yp,
                                               unsigned* __restrict__ rowkey) {
    int t = threadIdx.x;
    int nbase = blockIdx.x * (256 * T1);
    float x0[T1], x1[T1], x2[T1];
    unsigned kmin[T1];
#pragma unroll
    for (int k = 0; k < T1; ++k) {
        float4 xv = xp[nbase + t + k * 256];
        x0[k] = xv.x; x1[k] = xv.y; x2[k] = xv.z;
        kmin[k] = 0xFFFFFFFFu;
    }
    int m0 = blockIdx.y * (MP / CA);
    int m1 = m0 + (MP / CA);
#pragma unroll 2
    for (int m = m0; m < m1; ++m) {
        float4 yv = yp[m];  // wave-uniform address
        float y0 = yv.x, y1 = yv.y, y2 = yv.z;
#pragma unroll
        for (int k = 0; k < T1; ++k) {
            float dx = x0[k] - y0;
            float dy = x1[k] - y1;
            float dz = x2[k] - y2;
            float d2 = fmaf(dx, dx, fmaf(dy, dy, dz * dz));  // >= 0 by construction
            unsigned key = (__float_as_uint(d2) & 0xFFFFE000u) | (unsigned)m;
            kmin[k] = key < kmin[k] ? key : kmin[k];
        }
    }
#pragma unroll
    for (int k = 0; k < T1; ++k) atomicMin(&rowkey[nbase + t + k * 256], kmin[k]);
}

// cols: each thread owns T2=8 m-points (block-strided), loops over an n-chunk.
__global__ __launch_bounds__(256) void k2_cols(const float4* __restrict__ xp,
                                               const float4* __restrict__ yp,
                                               unsigned* __restrict__ colbits) {
    int t = threadIdx.x;
    int mbase = blockIdx.x * (256 * T2);
    float y0[T2], y1[T2], y2[T2], dmin[T2];
#pragma unroll
    for (int k = 0; k < T2; ++k) {
        float4 yv = yp[mbase + t + k * 256];
        y0[k] = yv.x; y1[k] = yv.y; y2[k] = yv.z;
        dmin[k] = __builtin_inff();
    }
    int n0 = blockIdx.y * (NP / CB);
    int n1 = n0 + (NP / CB);
#pragma unroll 2
    for (int n = n0; n < n1; ++n) {
        float4 xv = xp[n];  // wave-uniform address
        float xx0 = xv.x, xx1 = xv.y, xx2 = xv.z;
#pragma unroll
        for (int k = 0; k < T2; ++k) {
            float dx = xx0 - y0[k];
            float dy = xx1 - y1[k];
            float dz = xx2 - y2[k];
            float d2 = fmaf(dx, dx, fmaf(dy, dy, dz * dz));
            dmin[k] = fminf(dmin[k], d2);
        }
    }
#pragma unroll
    for (int k = 0; k < T2; ++k)
        atomicMin(&colbits[mbase + t + k * 256], __float_as_uint(dmin[k]));
}

__global__ __launch_bounds__(256) void k3_reduce(const unsigned* __restrict__ rowkey,
                                                 const unsigned* __restrict__ colbits,
                                                 const float* __restrict__ probs,
                                                 float* __restrict__ out) {
    int i = blockIdx.x * 256 + threadIdx.x;
    float v = 0.f;
    if (i < NP) {
        unsigned k = rowkey[i];
        unsigned idx = k & 0x1FFFu;
        float dmin = __uint_as_float(k & 0xFFFFE000u);
        v = probs[idx] * dmin;  // l2 contribution
    } else {
        int m = i - NP;  // m < MP by grid construction
        float dmin = __uint_as_float(colbits[m]);
        v = probs[m] * dmin;  // l1 contribution
    }
    for (int off = 32; off > 0; off >>= 1) v += __shfl_down(v, off, 64);
    __shared__ float wsum[4];
    int lane = threadIdx.x & 63;
    int w = threadIdx.x >> 6;
    if (lane == 0) wsum[w] = v;
    __syncthreads();
    if (threadIdx.x == 0) {
        atomicAdd(out, wsum[0] + wsum[1] + wsum[2] + wsum[3]);
    }
}

extern "C" void kernel_launch(void* const* d_in, const int* in_sizes, int n_in,
                              void* d_out, int out_size, void* d_ws, size_t ws_size,
                              hipStream_t stream) {
    const float* x = (const float*)d_in[0];      // [N,3]
    const float* y = (const float*)d_in[1];      // [M,3]
    const float* probs = (const float*)d_in[2];  // [M]
    float* out = (float*)d_out;

    char* ws = (char*)d_ws;
    unsigned* rowkey = (unsigned*)ws;
    unsigned* colbits = (unsigned*)(ws + (size_t)NP * 4);
    float4* xp = (float4*)(ws + (size_t)NP * 4 + (size_t)MP * 4);
    float4* yp = (float4*)(ws + (size_t)NP * 4 + (size_t)MP * 4 + (size_t)NP * 16);

    k0_init<<<NP / 256, 256, 0, stream>>>(x, y, rowkey, colbits, xp, yp, out);
    k1_rows<<<dim3(NP / (256 * T1), CA), 256, 0, stream>>>(xp, yp, rowkey);
    k2_cols<<<dim3(MP / (256 * T2), CB), 256, 0, stream>>>(xp, yp, colbits);
    k3_reduce<<<(NP + MP) / 256, 256, 0, stream>>>(rowkey, colbits, probs, out);
}

// Round 3
// 144.454 us; speedup vs baseline: 3.1403x; 1.2696x over previous
//
#include <hip/hip_runtime.h>

// Chamfer distance loss, brute force, fp32 VALU, register-tiled (T=8),
// k1+k2 fused into one dispatch, dot-form distances with precomputed norms.
// N=65536 vertices (x), M=8192 samples (y), D=3.
// l1 = sum_m probs[m] * min_n d2(n,m)
// l2 = sum_n probs[argmin_m d2(n,m)] * min_m d2(n,m)
// out = l1 + l2  (single f32)

constexpr int NP = 65536;
constexpr int MP = 8192;
constexpr int T = 8;     // points per thread (both phases)
constexpr int CA = 32;   // m-chunks for rows: per-thread m-loop = MP/CA = 256
constexpr int CB = 256;  // n-chunks for cols: per-thread n-loop = NP/CB = 256
constexpr int NB_ROW = (NP / (256 * T));        // 32 n-block groups
constexpr int NB_COL = (MP / (256 * T));        // 4 m-block groups
constexpr int B1 = NB_ROW * CA;                 // 1024 row blocks
constexpr int B2 = NB_COL * CB;                 // 1024 col blocks

// ws layout (bytes):
//   [0,         NP*4)            rowkey  (uint per n: d2bits&~0x1FFF | m)
//   [NP*4,      NP*4+MP*4)       colbits (uint per m: float bits of min d2)
//   [+,         +NP*16)          xp (float4: x,y,z,||x||^2)
//   [+,         +MP*16)          yp (float4: y,x,z,||y||^2)

__global__ __launch_bounds__(256) void k0_init(const float* __restrict__ x,
                                               const float* __restrict__ y,
                                               unsigned* __restrict__ rowkey,
                                               unsigned* __restrict__ colbits,
                                               float4* __restrict__ xp,
                                               float4* __restrict__ yp,
                                               float* __restrict__ out) {
    int i = blockIdx.x * 256 + threadIdx.x;
    if (i < NP) {
        rowkey[i] = 0xFFFFFFFFu;
        float a = x[i * 3 + 0], b = x[i * 3 + 1], c = x[i * 3 + 2];
        xp[i] = make_float4(a, b, c, fmaf(a, a, fmaf(b, b, c * c)));
    }
    if (i < MP) {
        colbits[i] = 0x7F800000u;  // +inf
        float a = y[i * 3 + 0], b = y[i * 3 + 1], c = y[i * 3 + 2];
        yp[i] = make_float4(a, b, c, fmaf(a, a, fmaf(b, b, c * c)));
    }
    if (i == 0) out[0] = 0.f;
}

// Fused pair-distance kernel. Blocks [0,B1): rows (per-n argmin over m).
// Blocks [B1,B1+B2): cols (per-m min over n). Each thread owns T=8 points
// (block-strided); inner loop reads one opposing point (uniform -> s_load)
// shared across 8 chains.
__global__ __launch_bounds__(256, 8) void k12_pairs(const float4* __restrict__ xp,
                                                    const float4* __restrict__ yp,
                                                    unsigned* __restrict__ rowkey,
                                                    unsigned* __restrict__ colbits) {
    int t = threadIdx.x;
    if (blockIdx.x < B1) {
        // ---- rows: thread owns 8 n-points, scans an m-chunk ----
        int bx = blockIdx.x & (NB_ROW - 1);
        int by = blockIdx.x / NB_ROW;
        int nbase = bx * (256 * T);
        float x0[T], x1[T], x2[T], xw[T];
        unsigned kmin[T];
#pragma unroll
        for (int k = 0; k < T; ++k) {
            float4 xv = xp[nbase + t + k * 256];
            x0[k] = xv.x; x1[k] = xv.y; x2[k] = xv.z; xw[k] = xv.w;
            kmin[k] = 0xFFFFFFFFu;
        }
        int m0 = by * (MP / CA);
        int m1 = m0 + (MP / CA);
#pragma unroll 4
        for (int m = m0; m < m1; ++m) {
            float4 yv = yp[m];  // wave-uniform address
#pragma unroll
            for (int k = 0; k < T; ++k) {
                float s = fmaf(x0[k], yv.x, fmaf(x1[k], yv.y, x2[k] * yv.z));
                float c = xw[k] + yv.w;
                float d2 = fmaf(s, -2.f, c);  // tiny negatives lose the min: harmless
                unsigned key = (__float_as_uint(d2) & 0xFFFFE000u) | (unsigned)m;
                kmin[k] = key < kmin[k] ? key : kmin[k];
            }
        }
#pragma unroll
        for (int k = 0; k < T; ++k) atomicMin(&rowkey[nbase + t + k * 256], kmin[k]);
    } else {
        // ---- cols: thread owns 8 m-points, scans an n-chunk ----
        int b = blockIdx.x - B1;
        int bx = b & (NB_COL - 1);
        int by = b / NB_COL;
        int mbase = bx * (256 * T);
        float y0[T], y1[T], y2[T], yw[T], dmin[T];
#pragma unroll
        for (int k = 0; k < T; ++k) {
            float4 yv = yp[mbase + t + k * 256];
            y0[k] = yv.x; y1[k] = yv.y; y2[k] = yv.z; yw[k] = yv.w;
            dmin[k] = __builtin_inff();
        }
        int n0 = by * (NP / CB);
        int n1 = n0 + (NP / CB);
#pragma unroll 4
        for (int n = n0; n < n1; ++n) {
            float4 xv = xp[n];  // wave-uniform address
#pragma unroll
            for (int k = 0; k < T; ++k) {
                float s = fmaf(y0[k], xv.x, fmaf(y1[k], xv.y, y2[k] * xv.z));
                float d = fmaf(s, -2.f, xv.w);  // x2n - 2 x.y (y2 folded at end)
                dmin[k] = fminf(dmin[k], d);
            }
        }
#pragma unroll
        for (int k = 0; k < T; ++k) {
            float d2 = fmaxf(dmin[k] + yw[k], 0.f);  // clamp commutes with min
            atomicMin(&colbits[mbase + t + k * 256], __float_as_uint(d2));
        }
    }
}

__global__ __launch_bounds__(256) void k3_reduce(const unsigned* __restrict__ rowkey,
                                                 const unsigned* __restrict__ colbits,
                                                 const float* __restrict__ probs,
                                                 float* __restrict__ out) {
    int i = blockIdx.x * 256 + threadIdx.x;
    float v = 0.f;
    if (i < NP) {
        unsigned k = rowkey[i];
        unsigned idx = k & 0x1FFFu;
        float dmin = __uint_as_float(k & 0xFFFFE000u);
        v = probs[idx] * dmin;  // l2 contribution
    } else {
        int m = i - NP;  // m < MP by grid construction
        float dmin = __uint_as_float(colbits[m]);
        v = probs[m] * dmin;  // l1 contribution
    }
    for (int off = 32; off > 0; off >>= 1) v += __shfl_down(v, off, 64);
    __shared__ float wsum[4];
    int lane = threadIdx.x & 63;
    int w = threadIdx.x >> 6;
    if (lane == 0) wsum[w] = v;
    __syncthreads();
    if (threadIdx.x == 0) {
        atomicAdd(out, wsum[0] + wsum[1] + wsum[2] + wsum[3]);
    }
}

extern "C" void kernel_launch(void* const* d_in, const int* in_sizes, int n_in,
                              void* d_out, int out_size, void* d_ws, size_t ws_size,
                              hipStream_t stream) {
    const float* x = (const float*)d_in[0];      // [N,3]
    const float* y = (const float*)d_in[1];      // [M,3]
    const float* probs = (const float*)d_in[2];  // [M]
    float* out = (float*)d_out;

    char* ws = (char*)d_ws;
    unsigned* rowkey = (unsigned*)ws;
    unsigned* colbits = (unsigned*)(ws + (size_t)NP * 4);
    float4* xp = (float4*)(ws + (size_t)NP * 4 + (size_t)MP * 4);
    float4* yp = (float4*)(ws + (size_t)NP * 4 + (size_t)MP * 4 + (size_t)NP * 16);

    k0_init<<<NP / 256, 256, 0, stream>>>(x, y, rowkey, colbits, xp, yp, out);
    k12_pairs<<<B1 + B2, 256, 0, stream>>>(xp, yp, rowkey, colbits);
    k3_reduce<<<(NP + MP) / 256, 256, 0, stream>>>(rowkey, colbits, probs, out);
}